// Round 7
// baseline (242.936 us; speedup 1.0000x reference)
//
#include <hip/hip_runtime.h>
#include <cmath>

constexpr int Bn = 512, Cn = 256, Tn = 256, En = 8;
constexpr float EPSf = 1e-5f;

using bf16x8 = __attribute__((ext_vector_type(8))) short;
using f32x4  = __attribute__((ext_vector_type(4))) float;

__device__ __forceinline__ ushort f2bf(float f) {
    uint u = __builtin_bit_cast(uint, f);
    uint r = u + 0x7FFFu + ((u >> 16) & 1u);   // RNE
    return (ushort)(r >> 16);
}

// Pre-kernel 1: W fp32 [E][co][ci][K] -> Wws bf16 [E][k][co][ci]
__global__ __launch_bounds__(256)
void wconv_kernel(const float* __restrict__ Wf, ushort* __restrict__ Wws) {
    int idx = blockIdx.x * 256 + threadIdx.x;   // e*65536 + co*256 + ci
    const float* src = Wf + (size_t)idx * 5;
    int ci = idx & 255, co = (idx >> 8) & 255, e = idx >> 16;
#pragma unroll
    for (int k = 0; k < 5; ++k)
        Wws[(((size_t)(e * 5 + k) * 256 + co) << 8) + ci] = f2bf(src[k]);
}

// Pre-kernel 2: x fp32 [B][ci][t] -> xT bf16 [B][t][ci] (64ci x 32t tiles)
__global__ __launch_bounds__(256)
void xpose_kernel(const float* __restrict__ x, ushort* __restrict__ xT) {
    const int id = blockIdx.x;            // 512 b x 4 ciC x 8 tC
    const int b  = id >> 5;
    const int cc = (id >> 3) & 3, tc = id & 7;
    const int ci0 = cc * 64, t0 = tc * 32;
    const int tid = threadIdx.x;

    __shared__ float ls[64][33];

    const int tl = tid & 31;              // t within tile (load phase)
#pragma unroll
    for (int jj = 0; jj < 8; ++jj) {
        const int cil = (tid >> 5) * 8 + jj;
        ls[cil][tl] = x[((size_t)(b * 256 + ci0 + cil)) * 256 + t0 + tl];
    }
    __syncthreads();

    const int ciw = tid & 63;             // ci within tile (store phase)
#pragma unroll
    for (int jj = 0; jj < 8; ++jj) {
        const int tw = (tid >> 6) * 8 + jj;
        xT[((size_t)(b * 256 + t0 + tw)) * 256 + ci0 + ciw] = f2bf(ls[ciw][tw]);
    }
}

// Fused conv+GroupNorm+Mish. Block = (b, group-pair gp): co [gp*64,+64), all t.
// 2048 blocks x 256 thr (4 waves); wave w owns t-slice [w*64,+64).
// Per wave: 4m x 4n frags of 16x16x32 (acc 64 AGPR).
// LDS xT dbuf [2][260][40] ushort (row t+2 = x[t], halo rows zero).
// MODE 2: stage from pre-transposed bf16 xT_ws (4 x 16B loads + 4 ds_write_b128
// per thread per tile, no VALU). MODE 1: f2bf staging, Wws. MODE 0: all inline.
template<int MODE>
__global__ __launch_bounds__(256, 3)
void conv_gn_mish(const float* __restrict__ x, const ushort* __restrict__ xTw,
                  const int* __restrict__ expert,
                  const float* __restrict__ Wf, const ushort* __restrict__ Wws,
                  const float* __restrict__ bias, const float* __restrict__ gamma,
                  const float* __restrict__ beta, float* __restrict__ out)
{
    const int id = blockIdx.x;
    const int wg = (id & 7) * 256 + (id >> 3);   // XCD-chunk swizzle (2048=8*256)
    const int b  = wg >> 2;
    const int gp = wg & 3;
    const int cb = gp * 64;
    const int e  = __builtin_amdgcn_readfirstlane(expert[b]);

    const int tid = threadIdx.x;
    const int w = tid >> 6, l = tid & 63, q = l >> 4, r = l & 15;

    __shared__ ushort xT[2][260 * 40];
    __shared__ float red[4][4];

    f32x4 acc[4][4];
#pragma unroll
    for (int m = 0; m < 4; ++m)
#pragma unroll
        for (int n = 0; n < 4; ++n) acc[m][n] = f32x4{0.f, 0.f, 0.f, 0.f};

    // zero halo rows (t' = 0,1,258,259) in BOTH buffers; never overwritten
    if (tid < 8) {
        const int bf = tid >> 2, rr = tid & 3;
        const int row = (rr < 2) ? rr : (256 + rr);
#pragma unroll
        for (int i = 0; i < 10; ++i)
            *reinterpret_cast<uint2*>(&xT[bf][row * 40 + i * 4]) = make_uint2(0u, 0u);
    }

    bf16x8 g[4];     // MODE 2 staging: g[tt] = xT_ws[b][tt*64+l][ci0 + w*8 ..+8)
    float v[4][8];   // MODE<2 staging

#define STAGE_LOAD(CI0) {                                                    \
        if (MODE == 2) {                                                     \
            const ushort* xb = xTw + ((size_t)b * 256) * 256 + (CI0) + w * 8;\
            _Pragma("unroll")                                                \
            for (int tt = 0; tt < 4; ++tt)                                   \
                g[tt] = *reinterpret_cast<const bf16x8*>(                    \
                    xb + (size_t)(tt * 64 + l) * 256);                       \
        } else {                                                             \
            const float* xb = x + ((size_t)b * Cn + (CI0) + w * 8) * Tn;     \
            _Pragma("unroll")                                                \
            for (int tt = 0; tt < 4; ++tt) {                                 \
                const int t = tt * 64 + l;                                   \
                _Pragma("unroll")                                            \
                for (int rr = 0; rr < 8; ++rr) v[tt][rr] = xb[rr * Tn + t];  \
            }                                                                \
        }                                                                    \
    }
#define STAGE_WRITE(BUF) {                                                   \
        ushort* dst = xT[BUF];                                               \
        if (MODE == 2) {                                                     \
            _Pragma("unroll")                                                \
            for (int tt = 0; tt < 4; ++tt)                                   \
                *reinterpret_cast<bf16x8*>(                                  \
                    &dst[(tt * 64 + l + 2) * 40 + w * 8]) = g[tt];           \
        } else {                                                             \
            _Pragma("unroll")                                                \
            for (int tt = 0; tt < 4; ++tt) {                                 \
                const int t = tt * 64 + l;                                   \
                uint p0 = (uint)f2bf(v[tt][0]) | ((uint)f2bf(v[tt][1]) << 16); \
                uint p1 = (uint)f2bf(v[tt][2]) | ((uint)f2bf(v[tt][3]) << 16); \
                uint p2 = (uint)f2bf(v[tt][4]) | ((uint)f2bf(v[tt][5]) << 16); \
                uint p3 = (uint)f2bf(v[tt][6]) | ((uint)f2bf(v[tt][7]) << 16); \
                *reinterpret_cast<uint2*>(&dst[(t + 2) * 40 + w * 8])     = make_uint2(p0, p1); \
                *reinterpret_cast<uint2*>(&dst[(t + 2) * 40 + w * 8 + 4]) = make_uint2(p2, p3); \
            }                                                                \
        }                                                                    \
    }

    STAGE_LOAD(0);
    STAGE_WRITE(0);
    STAGE_LOAD(32);
    __syncthreads();

#pragma unroll 1
    for (int ct = 0; ct < 8; ++ct) {
        if (ct < 7) {
            STAGE_WRITE((ct + 1) & 1);
            if (ct < 6) STAGE_LOAD((ct + 2) * 32);   // 2-tile lookahead
        }
        const int ci0 = ct * 32;
        const ushort* src = xT[ct & 1];

#pragma unroll
        for (int k = 0; k < 5; ++k) {
            bf16x8 A[4];
#pragma unroll
            for (int m = 0; m < 4; ++m) {
                if (MODE >= 1) {
                    A[m] = *reinterpret_cast<const bf16x8*>(
                        Wws + (((size_t)((e * 5 + k) * 256 + cb + m * 16 + r)) << 8)
                            + ci0 + q * 8);
                } else {
                    bf16x8 a;
#pragma unroll
                    for (int j = 0; j < 8; ++j)
                        a[j] = (short)f2bf(
                            Wf[((size_t)(e * 256 + cb + m * 16 + r) * 256
                                + ci0 + q * 8 + j) * 5 + k]);
                    A[m] = a;
                }
            }
#pragma unroll
            for (int n = 0; n < 4; ++n) {
                const bf16x8 Bf = *reinterpret_cast<const bf16x8*>(
                    &src[(w * 64 + n * 16 + r + k) * 40 + q * 8]);
#pragma unroll
                for (int m = 0; m < 4; ++m)
                    acc[m][n] = __builtin_amdgcn_mfma_f32_16x16x32_bf16(
                        A[m], Bf, acc[m][n], 0, 0, 0);
            }
        }
        __syncthreads();
    }
#undef STAGE_LOAD
#undef STAGE_WRITE

    // ---- bias + GroupNorm stats (group A: m 0,1 -> co cb..cb+31; B: m 2,3) ----
    float s1a = 0.f, s2a = 0.f, s1b = 0.f, s2b = 0.f;
#pragma unroll
    for (int m = 0; m < 4; ++m) {
#pragma unroll
        for (int i = 0; i < 4; ++i) {
            const float bv = bias[e * Cn + cb + m * 16 + q * 4 + i];
#pragma unroll
            for (int n = 0; n < 4; ++n) {
                const float val = acc[m][n][i] + bv;
                acc[m][n][i] = val;
                if (m < 2) { s1a += val; s2a += val * val; }
                else       { s1b += val; s2b += val * val; }
            }
        }
    }
#pragma unroll
    for (int off = 32; off; off >>= 1) {
        s1a += __shfl_xor(s1a, off); s2a += __shfl_xor(s2a, off);
        s1b += __shfl_xor(s1b, off); s2b += __shfl_xor(s2b, off);
    }
    if (l == 0) { red[w][0] = s1a; red[w][1] = s2a; red[w][2] = s1b; red[w][3] = s2b; }
    __syncthreads();
    const float S1a = red[0][0] + red[1][0] + red[2][0] + red[3][0];
    const float S2a = red[0][1] + red[1][1] + red[2][1] + red[3][1];
    const float S1b = red[0][2] + red[1][2] + red[2][2] + red[3][2];
    const float S2b = red[0][3] + red[1][3] + red[2][3] + red[3][3];

    constexpr float invn = 1.0f / (32 * 256);
    const float mua = S1a * invn, mub = S1b * invn;
    const float rsa = rsqrtf(fmaf(-mua, mua, S2a * invn) + EPSf);
    const float rsb = rsqrtf(fmaf(-mub, mub, S2b * invn) + EPSf);

    // ---- normalize + Mish + store ----
#pragma unroll
    for (int m = 0; m < 4; ++m) {
        const float mu = (m < 2) ? mua : mub;
        const float rs = (m < 2) ? rsa : rsb;
#pragma unroll
        for (int i = 0; i < 4; ++i) {
            const int co = cb + m * 16 + q * 4 + i;
            const float sc = gamma[e * Cn + co] * rs;
            const float sh = beta[e * Cn + co] - mu * sc;
            float* orow = out + ((size_t)(b * Cn + co)) * Tn + w * 64 + r;
#pragma unroll
            for (int n = 0; n < 4; ++n) {
                const float y = fmaf(acc[m][n][i], sc, sh);
                const float u  = __expf(y);
                const float t2 = u * (u + 2.f);
                const float ms = (y > 20.f) ? y : y * t2 / (t2 + 2.f);
                orow[n * 16] = ms;
            }
        }
    }
}

extern "C" void kernel_launch(void* const* d_in, const int* in_sizes, int n_in,
                              void* d_out, int out_size, void* d_ws, size_t ws_size,
                              hipStream_t stream) {
    const float* x      = (const float*)d_in[0];
    const int*   expert = (const int*)  d_in[1];
    const float* Wf     = (const float*)d_in[2];
    const float* bias   = (const float*)d_in[3];
    const float* gamma  = (const float*)d_in[4];
    const float* beta   = (const float*)d_in[5];
    float* out = (float*)d_out;

    const size_t WWS_BYTES = (size_t)En * 5 * 256 * 256 * 2;      //  5,242,880
    const size_t XT_BYTES  = (size_t)Bn * 256 * 256 * 2;          // 67,108,864

    ushort* Wws = (ushort*)d_ws;
    ushort* xTw = (ushort*)((char*)d_ws + WWS_BYTES);

    if (ws_size >= WWS_BYTES + XT_BYTES) {
        hipLaunchKernelGGL(wconv_kernel, dim3(2048), dim3(256), 0, stream, Wf, Wws);
        hipLaunchKernelGGL(xpose_kernel, dim3(16384), dim3(256), 0, stream, x, xTw);
        hipLaunchKernelGGL((conv_gn_mish<2>), dim3(2048), dim3(256), 0, stream,
                           x, xTw, expert, Wf, Wws, bias, gamma, beta, out);
    } else if (ws_size >= WWS_BYTES) {
        hipLaunchKernelGGL(wconv_kernel, dim3(2048), dim3(256), 0, stream, Wf, Wws);
        hipLaunchKernelGGL((conv_gn_mish<1>), dim3(2048), dim3(256), 0, stream,
                           x, nullptr, expert, Wf, Wws, bias, gamma, beta, out);
    } else {
        hipLaunchKernelGGL((conv_gn_mish<0>), dim3(2048), dim3(256), 0, stream,
                           x, nullptr, expert, Wf, nullptr, bias, gamma, beta, out);
    }
}

// Round 8
// 225.295 us; speedup vs baseline: 1.0783x; 1.0783x over previous
//
#include <hip/hip_runtime.h>
#include <cmath>

constexpr int Bn = 512, Cn = 256, Tn = 256, En = 8;
constexpr float EPSf = 1e-5f;

using bf16x8 = __attribute__((ext_vector_type(8))) short;
using f32x4  = __attribute__((ext_vector_type(4))) float;

__device__ __forceinline__ ushort f2bf(float f) {
    uint u = __builtin_bit_cast(uint, f);
    uint r = u + 0x7FFFu + ((u >> 16) & 1u);   // RNE
    return (ushort)(r >> 16);
}

// Pre-kernel 1: W fp32 [E][co][ci][K] -> Wws bf16 [E][k][co][ci]
__global__ __launch_bounds__(256)
void wconv_kernel(const float* __restrict__ Wf, ushort* __restrict__ Wws) {
    int idx = blockIdx.x * 256 + threadIdx.x;   // e*65536 + co*256 + ci
    const float* src = Wf + (size_t)idx * 5;
    int ci = idx & 255, co = (idx >> 8) & 255, e = idx >> 16;
#pragma unroll
    for (int k = 0; k < 5; ++k)
        Wws[(((size_t)(e * 5 + k) * 256 + co) << 8) + ci] = f2bf(src[k]);
}

// Pre-kernel 2: x fp32 [B][ci][t] -> xT bf16 [B][t][ci] (64ci x 32t tiles)
__global__ __launch_bounds__(256)
void xpose_kernel(const float* __restrict__ x, ushort* __restrict__ xT) {
    const int id = blockIdx.x;            // 512 b x 4 ciC x 8 tC
    const int b  = id >> 5;
    const int cc = (id >> 3) & 3, tc = id & 7;
    const int ci0 = cc * 64, t0 = tc * 32;
    const int tid = threadIdx.x;

    __shared__ float ls[64][33];

    const int tl = tid & 31;              // t within tile (load phase)
#pragma unroll
    for (int jj = 0; jj < 8; ++jj) {
        const int cil = (tid >> 5) * 8 + jj;
        ls[cil][tl] = x[((size_t)(b * 256 + ci0 + cil)) * 256 + t0 + tl];
    }
    __syncthreads();

    const int ciw = tid & 63;             // ci within tile (store phase)
#pragma unroll
    for (int jj = 0; jj < 8; ++jj) {
        const int tw = (tid >> 6) * 8 + jj;
        xT[((size_t)(b * 256 + t0 + tw)) * 256 + ci0 + ciw] = f2bf(ls[ciw][tw]);
    }
}

// Fused conv+GroupNorm+Mish. Block = (b, group-pair gp): co [gp*64,+64), all t.
// 2048 blocks x 256 thr (4 waves); wave w owns t-slice [w*64,+64).
// WAVE-PRIVATE staging: each wave double-buffers its own 68-row x-tile
// ([40]-ushort stride, rows = t - tw + 2, OOB rows zeroed). A wave only reads
// LDS it wrote -> NO __syncthreads in the K-loop (wave-internal lgkm order).
// Per wave: 4m x 4n frags of 16x16x32, acc 64 VGPR.
// Pipeline/iter: WRITE(ct+1) [vmcnt drain]; LOAD(ct+2) in flight; MFMA(ct).
template<int MODE>   // 2: bf16 xT ws, 1: f2bf staging + Wws, 0: all inline
__global__ __launch_bounds__(256, 3)
void conv_gn_mish(const float* __restrict__ x, const ushort* __restrict__ xTw,
                  const int* __restrict__ expert,
                  const float* __restrict__ Wf, const ushort* __restrict__ Wws,
                  const float* __restrict__ bias, const float* __restrict__ gamma,
                  const float* __restrict__ beta, float* __restrict__ out)
{
    const int id = blockIdx.x;
    const int wg = (id & 7) * 256 + (id >> 3);   // XCD-chunk swizzle (2048=8*256)
    const int b  = wg >> 2;
    const int gp = wg & 3;
    const int cb = gp * 64;
    const int e  = __builtin_amdgcn_readfirstlane(expert[b]);

    const int tid = threadIdx.x;
    const int w = tid >> 6, l = tid & 63, q = l >> 4, r = l & 15;
    const int tw = w * 64;

    __shared__ ushort xw[4][2][68 * 40];
    __shared__ float red[4][4];

    f32x4 acc[4][4];
#pragma unroll
    for (int m = 0; m < 4; ++m)
#pragma unroll
        for (int n = 0; n < 4; ++n) acc[m][n] = f32x4{0.f, 0.f, 0.f, 0.f};

    // staging lane map: 5 issues j; row = j*16 + (l>>2), slot (l&3)*8 ci
    const int srow = l >> 2;
    const int slot = l & 3;
    const bf16x8 zv = {0, 0, 0, 0, 0, 0, 0, 0};
    bf16x8 g[5];

#define STAGE_LOAD(CI0) {                                                    \
        _Pragma("unroll")                                                    \
        for (int j = 0; j < 5; ++j) {                                        \
            const int row = j * 16 + srow;                                   \
            const int t = tw - 2 + row;                                      \
            const bool ok = (row < 68) && (t >= 0) && (t < Tn);              \
            if (MODE == 2) {                                                 \
                g[j] = ok ? *reinterpret_cast<const bf16x8*>(                \
                    xTw + ((size_t)(b * 256 + t)) * 256 + (CI0) + slot * 8)  \
                          : zv;                                              \
            } else {                                                         \
                bf16x8 a = zv;                                               \
                if (ok) {                                                    \
                    const float* xp = x + ((size_t)b * Cn + (CI0) + slot * 8) * Tn + t; \
                    _Pragma("unroll")                                        \
                    for (int jj = 0; jj < 8; ++jj)                           \
                        a[jj] = (short)f2bf(xp[jj * Tn]);                    \
                }                                                            \
                g[j] = a;                                                    \
            }                                                                \
        }                                                                    \
    }
#define STAGE_WRITE(BUF) {                                                   \
        ushort* dst = &xw[w][BUF][0];                                        \
        _Pragma("unroll")                                                    \
        for (int j = 0; j < 5; ++j) {                                        \
            const int row = j * 16 + srow;                                   \
            if (row < 68)                                                    \
                *reinterpret_cast<bf16x8*>(dst + row * 40 + slot * 8) = g[j];\
        }                                                                    \
    }

    STAGE_LOAD(0);
    STAGE_WRITE(0);
    STAGE_LOAD(32);

#pragma unroll 1
    for (int ct = 0; ct < 8; ++ct) {
        if (ct < 7) {
            STAGE_WRITE((ct + 1) & 1);            // drains vmcnt of LOAD(ct+1)
            if (ct < 6) STAGE_LOAD((ct + 2) * 32);// in flight across MFMA(ct)
        }
        const int ci0 = ct * 32;
        const ushort* src = &xw[w][ct & 1][0];

#pragma unroll
        for (int k = 0; k < 5; ++k) {
            bf16x8 A[4];
#pragma unroll
            for (int m = 0; m < 4; ++m) {
                if (MODE >= 1) {
                    A[m] = *reinterpret_cast<const bf16x8*>(
                        Wws + (((size_t)((e * 5 + k) * 256 + cb + m * 16 + r)) << 8)
                            + ci0 + q * 8);
                } else {
                    bf16x8 a;
#pragma unroll
                    for (int j = 0; j < 8; ++j)
                        a[j] = (short)f2bf(
                            Wf[((size_t)(e * 256 + cb + m * 16 + r) * 256
                                + ci0 + q * 8 + j) * 5 + k]);
                    A[m] = a;
                }
            }
#pragma unroll
            for (int n = 0; n < 4; ++n) {
                const bf16x8 Bf = *reinterpret_cast<const bf16x8*>(
                    &src[(n * 16 + r + k) * 40 + q * 8]);
#pragma unroll
                for (int m = 0; m < 4; ++m)
                    acc[m][n] = __builtin_amdgcn_mfma_f32_16x16x32_bf16(
                        A[m], Bf, acc[m][n], 0, 0, 0);
            }
        }
    }
#undef STAGE_LOAD
#undef STAGE_WRITE

    // ---- bias + GroupNorm stats (group A: m 0,1 -> co cb..cb+31; B: m 2,3) ----
    float s1a = 0.f, s2a = 0.f, s1b = 0.f, s2b = 0.f;
#pragma unroll
    for (int m = 0; m < 4; ++m) {
#pragma unroll
        for (int i = 0; i < 4; ++i) {
            const float bv = bias[e * Cn + cb + m * 16 + q * 4 + i];
#pragma unroll
            for (int n = 0; n < 4; ++n) {
                const float val = acc[m][n][i] + bv;
                acc[m][n][i] = val;
                if (m < 2) { s1a += val; s2a += val * val; }
                else       { s1b += val; s2b += val * val; }
            }
        }
    }
#pragma unroll
    for (int off = 32; off; off >>= 1) {
        s1a += __shfl_xor(s1a, off); s2a += __shfl_xor(s2a, off);
        s1b += __shfl_xor(s1b, off); s2b += __shfl_xor(s2b, off);
    }
    if (l == 0) { red[w][0] = s1a; red[w][1] = s2a; red[w][2] = s1b; red[w][3] = s2b; }
    __syncthreads();                               // ONLY block-wide sync
    const float S1a = red[0][0] + red[1][0] + red[2][0] + red[3][0];
    const float S2a = red[0][1] + red[1][1] + red[2][1] + red[3][1];
    const float S1b = red[0][2] + red[1][2] + red[2][2] + red[3][2];
    const float S2b = red[0][3] + red[1][3] + red[2][3] + red[3][3];

    constexpr float invn = 1.0f / (32 * 256);
    const float mua = S1a * invn, mub = S1b * invn;
    const float rsa = rsqrtf(fmaf(-mua, mua, S2a * invn) + EPSf);
    const float rsb = rsqrtf(fmaf(-mub, mub, S2b * invn) + EPSf);

    // ---- normalize + Mish + store ----
#pragma unroll
    for (int m = 0; m < 4; ++m) {
        const float mu = (m < 2) ? mua : mub;
        const float rs = (m < 2) ? rsa : rsb;
#pragma unroll
        for (int i = 0; i < 4; ++i) {
            const int co = cb + m * 16 + q * 4 + i;
            const float sc = gamma[e * Cn + co] * rs;
            const float sh = beta[e * Cn + co] - mu * sc;
            float* orow = out + ((size_t)(b * Cn + co)) * Tn + tw + r;
#pragma unroll
            for (int n = 0; n < 4; ++n) {
                const float y = fmaf(acc[m][n][i], sc, sh);
                const float u  = __expf(y);
                const float t2 = u * (u + 2.f);
                const float ms = (y > 20.f) ? y : y * t2 / (t2 + 2.f);
                orow[n * 16] = ms;
            }
        }
    }
}

extern "C" void kernel_launch(void* const* d_in, const int* in_sizes, int n_in,
                              void* d_out, int out_size, void* d_ws, size_t ws_size,
                              hipStream_t stream) {
    const float* x      = (const float*)d_in[0];
    const int*   expert = (const int*)  d_in[1];
    const float* Wf     = (const float*)d_in[2];
    const float* bias   = (const float*)d_in[3];
    const float* gamma  = (const float*)d_in[4];
    const float* beta   = (const float*)d_in[5];
    float* out = (float*)d_out;

    const size_t WWS_BYTES = (size_t)En * 5 * 256 * 256 * 2;      //  5,242,880
    const size_t XT_BYTES  = (size_t)Bn * 256 * 256 * 2;          // 67,108,864

    ushort* Wws = (ushort*)d_ws;
    ushort* xTw = (ushort*)((char*)d_ws + WWS_BYTES);

    if (ws_size >= WWS_BYTES + XT_BYTES) {
        hipLaunchKernelGGL(wconv_kernel, dim3(2048), dim3(256), 0, stream, Wf, Wws);
        hipLaunchKernelGGL(xpose_kernel, dim3(16384), dim3(256), 0, stream, x, xTw);
        hipLaunchKernelGGL((conv_gn_mish<2>), dim3(2048), dim3(256), 0, stream,
                           x, xTw, expert, Wf, Wws, bias, gamma, beta, out);
    } else if (ws_size >= WWS_BYTES) {
        hipLaunchKernelGGL(wconv_kernel, dim3(2048), dim3(256), 0, stream, Wf, Wws);
        hipLaunchKernelGGL((conv_gn_mish<1>), dim3(2048), dim3(256), 0, stream,
                           x, nullptr, expert, Wf, Wws, bias, gamma, beta, out);
    } else {
        hipLaunchKernelGGL((conv_gn_mish<0>), dim3(2048), dim3(256), 0, stream,
                           x, nullptr, expert, Wf, nullptr, bias, gamma, beta, out);
    }
}